// Round 12
// baseline (510.547 us; speedup 1.0000x reference)
//
#include <hip/hip_runtime.h>
#include <math.h>

#define NLAYER 4
#define DMODEL 640
#define DINNER 1280
#define DSTATE 16
#define DTRANK 40
#define DCONV  4
#define BATCH  64
#define SEQ    30
#define MTOK   (BATCH*SEQ)       // 1920
#define NPROJ  (2*DINNER)        // 2560
#define NDBL   (DTRANK+2*DSTATE) // 72
#define NDBLP  80                // padded N for x_proj MFMA
#define KSEGS  8
#define KSEG   (DINNER/KSEGS)    // 160
#define DTKP   64                // padded K for dt GEMM

// weight-conversion region sizes (in float4 quads)
#define Q1 (NLAYER*NPROJ*DMODEL/4)   // 1,638,400
#define Q2 (NLAYER*DMODEL*DINNER/4)  //   819,200
#define Q3 (NLAYER*NDBLP*DINNER/4)   //   102,400
#define Q4 (NLAYER*DINNER*DTKP/4)    //    81,920
#define WCTOT (Q1+Q2+Q3+Q4)          // 2,641,920 = 256*10320

typedef unsigned short u16;
typedef __bf16 bf16x8 __attribute__((ext_vector_type(8)));
typedef float  f32x4  __attribute__((ext_vector_type(4)));
typedef unsigned short u16x8 __attribute__((ext_vector_type(8)));

__device__ __forceinline__ float siluf(float x) {
    return x / (1.0f + __expf(-x));
}

__device__ __forceinline__ u16 f2bf(float f) {
    unsigned int u = __float_as_uint(f);
    u += 0x7fffu + ((u >> 16) & 1u);
    return (u16)(u >> 16);
}

__device__ __forceinline__ float bf2f(u16 b) {
    return __uint_as_float(((unsigned int)b) << 16);
}

// h[b,v,:] = x[b,(v + SEQ - vs[b]) % SEQ, :]
__global__ void k_permute(const float* __restrict__ x, const int* __restrict__ vs,
                          float* __restrict__ h) {
    int idx = blockIdx.x * blockDim.x + threadIdx.x;
    if (idx >= MTOK * DMODEL) return;
    int d  = idx % DMODEL;
    int mv = idx / DMODEL;
    int v  = mv % SEQ;
    int b  = mv / SEQ;
    int src = (v + SEQ - vs[b]) % SEQ;
    h[idx] = x[(b * SEQ + src) * DMODEL + d];
}

// single weight-conversion kernel: all bf16 weight buffers in one launch.
__global__ __launch_bounds__(256)
void k_wconv(const float* __restrict__ in_w, const float* __restrict__ out_w,
             const float* __restrict__ xp_w, const float* __restrict__ dt_w,
             u16* __restrict__ wbi, u16* __restrict__ wbo,
             u16* __restrict__ wbx, u16* __restrict__ wdt) {
    int i = blockIdx.x * 256 + threadIdx.x;
    if (i < Q1) {
        int j = i * 4;
        float4 v = *(const float4*)(in_w + j);
        ushort4 o;
        o.x = f2bf(v.x); o.y = f2bf(v.y); o.z = f2bf(v.z); o.w = f2bf(v.w);
        *(ushort4*)(wbi + j) = o;
    } else if (i < Q1 + Q2) {
        int j = (i - Q1) * 4;
        float4 v = *(const float4*)(out_w + j);
        ushort4 o;
        o.x = f2bf(v.x); o.y = f2bf(v.y); o.z = f2bf(v.z); o.w = f2bf(v.w);
        *(ushort4*)(wbo + j) = o;
    } else if (i < Q1 + Q2 + Q3) {
        int j = (i - Q1 - Q2) * 4;
        int layer = j / (NDBLP * DINNER);
        int rem   = j % (NDBLP * DINNER);
        int r = rem / DINNER, c = rem % DINNER;
        ushort4 o = make_ushort4(0, 0, 0, 0);
        if (r < NDBL) {
            float4 v = *(const float4*)(xp_w + ((size_t)layer * NDBL + r) * DINNER + c);
            o.x = f2bf(v.x); o.y = f2bf(v.y); o.z = f2bf(v.z); o.w = f2bf(v.w);
        }
        *(ushort4*)(wbx + j) = o;
    } else {
        int j = (i - Q1 - Q2 - Q3) * 4;
        int ld = j / DTKP;      // layer*1280 + d
        int c  = j % DTKP;
        ushort4 o = make_ushort4(0, 0, 0, 0);
        if (c < DTRANK) {
            float4 v = *(const float4*)(dt_w + (size_t)ld * DTRANK + c);
            o.x = f2bf(v.x); o.y = f2bf(v.y); o.z = f2bf(v.z); o.w = f2bf(v.w);
        }
        *(ushort4*)(wdt + j) = o;
    }
}

// one wave per token: xn_bf16 = h * rsqrt(mean(h^2)+eps) * w  (float2 loads)
__global__ __launch_bounds__(64)
void k_rmsnorm(const float* __restrict__ h, const float* __restrict__ w,
               u16* __restrict__ xn) {
    int m = blockIdx.x;
    int t = threadIdx.x;
    const float* row = h + (size_t)m * DMODEL;
    float2 vv[5];
    float ss = 0.f;
    #pragma unroll
    for (int i = 0; i < 5; ++i) {
        vv[i] = *(const float2*)(row + i * 128 + t * 2);
        ss += vv[i].x * vv[i].x + vv[i].y * vv[i].y;
    }
    #pragma unroll
    for (int o = 32; o > 0; o >>= 1) ss += __shfl_xor(ss, o, 64);
    float sc = rsqrtf(ss / DMODEL + 1e-5f);
    u16* outp = xn + (size_t)m * DMODEL;
    #pragma unroll
    for (int i = 0; i < 5; ++i) {
        int d = i * 128 + t * 2;
        float2 wv = *(const float2*)(w + d);
        ushort2 o;
        o.x = f2bf(vv[i].x * sc * wv.x);
        o.y = f2bf(vv[i].y * sc * wv.y);
        *(ushort2*)(outp + d) = o;
    }
}

// 128x128-tile bf16 MFMA GEMM, 512 threads (8 waves, 32x64 per wave).
// bf16 output. Used for in_proj. Grid (N/128, M/128).
__global__ __launch_bounds__(512)
void k_mfma512(const u16* __restrict__ A, int lda,
               const u16* __restrict__ W,
               u16* __restrict__ Cb, int N, int K) {
    __shared__ u16 As[128 * 32];
    __shared__ u16 Bs[128 * 32];
    const int t = threadIdx.x;
    const int w = t >> 6, l = t & 63;
    const int lane15 = l & 15, quad = l >> 4;
    const int wm = w >> 1, wn = w & 1;     // wm 0..3, wn 0..1
    const int m0 = blockIdx.y * 128, n0 = blockIdx.x * 128;

    f32x4 acc[2][4];
    #pragma unroll
    for (int i = 0; i < 2; ++i)
        #pragma unroll
        for (int j = 0; j < 4; ++j)
            acc[i][j] = (f32x4){0.f, 0.f, 0.f, 0.f};

    for (int k0 = 0; k0 < K; k0 += 32) {
        __syncthreads();
        #pragma unroll
        for (int q = 0; q < 2; ++q) {
            int c = q * 512 + t;               // 0..1023
            if (c < 512) {                     // A-tile: 128 rows x 4 chunks
                const u16* ga = A + (size_t)(m0 + (c >> 2)) * lda + k0 + (c & 3) * 8;
                __builtin_amdgcn_global_load_lds(
                    (const __attribute__((address_space(1))) void*)ga,
                    (__attribute__((address_space(3))) void*)&As[c * 8], 16, 0, 0);
            } else {
                int cb = c - 512;
                const u16* gb = W + (size_t)(n0 + (cb >> 2)) * K + k0 + (cb & 3) * 8;
                __builtin_amdgcn_global_load_lds(
                    (const __attribute__((address_space(1))) void*)gb,
                    (__attribute__((address_space(3))) void*)&Bs[cb * 8], 16, 0, 0);
            }
        }
        __syncthreads();

        bf16x8 af[2], bfrag[4];
        #pragma unroll
        for (int i = 0; i < 2; ++i)
            af[i] = *(const bf16x8*)&As[(wm * 32 + i * 16 + lane15) * 32 + quad * 8];
        #pragma unroll
        for (int j = 0; j < 4; ++j)
            bfrag[j] = *(const bf16x8*)&Bs[(wn * 64 + j * 16 + lane15) * 32 + quad * 8];
        #pragma unroll
        for (int i = 0; i < 2; ++i)
            #pragma unroll
            for (int j = 0; j < 4; ++j)
                acc[i][j] = __builtin_amdgcn_mfma_f32_16x16x32_bf16(
                    af[i], bfrag[j], acc[i][j], 0, 0, 0);
    }

    #pragma unroll
    for (int i = 0; i < 2; ++i) {
        #pragma unroll
        for (int r = 0; r < 4; ++r) {
            int row = m0 + wm * 32 + i * 16 + quad * 4 + r;
            #pragma unroll
            for (int j = 0; j < 4; ++j) {
                int col = n0 + wn * 64 + j * 16 + lane15;
                Cb[(size_t)row * N + col] = f2bf(acc[i][j][r]);
            }
        }
    }
}

// 64x64-tile bf16 MFMA GEMM, f32 out + resid (out_proj)
__global__ __launch_bounds__(256)
void k_mfma64(const u16* __restrict__ A, int lda,
              const u16* __restrict__ W,
              const float* __restrict__ resid,
              float* __restrict__ C, int N, int K) {
    __shared__ u16 As[64 * 32];
    __shared__ u16 Bs[64 * 32];
    const int t = threadIdx.x;
    const int w = t >> 6, l = t & 63;
    const int lane15 = l & 15, quad = l >> 4;
    const int wm = w >> 1, wn = w & 1;
    const int m0 = blockIdx.y * 64, n0 = blockIdx.x * 64;

    f32x4 acc[2][2];
    #pragma unroll
    for (int i = 0; i < 2; ++i)
        #pragma unroll
        for (int j = 0; j < 2; ++j)
            acc[i][j] = (f32x4){0.f, 0.f, 0.f, 0.f};

    for (int k0 = 0; k0 < K; k0 += 32) {
        __syncthreads();
        {
            int c = t;
            const u16* ga = A + (size_t)(m0 + (c >> 2)) * lda + k0 + (c & 3) * 8;
            __builtin_amdgcn_global_load_lds(
                (const __attribute__((address_space(1))) void*)ga,
                (__attribute__((address_space(3))) void*)&As[c * 8], 16, 0, 0);
            const u16* gb = W + (size_t)(n0 + (c >> 2)) * K + k0 + (c & 3) * 8;
            __builtin_amdgcn_global_load_lds(
                (const __attribute__((address_space(1))) void*)gb,
                (__attribute__((address_space(3))) void*)&Bs[c * 8], 16, 0, 0);
        }
        __syncthreads();

        bf16x8 af[2], bfrag[2];
        #pragma unroll
        for (int i = 0; i < 2; ++i)
            af[i] = *(const bf16x8*)&As[(wm * 32 + i * 16 + lane15) * 32 + quad * 8];
        #pragma unroll
        for (int j = 0; j < 2; ++j)
            bfrag[j] = *(const bf16x8*)&Bs[(wn * 32 + j * 16 + lane15) * 32 + quad * 8];
        #pragma unroll
        for (int i = 0; i < 2; ++i)
            #pragma unroll
            for (int j = 0; j < 2; ++j)
                acc[i][j] = __builtin_amdgcn_mfma_f32_16x16x32_bf16(
                    af[i], bfrag[j], acc[i][j], 0, 0, 0);
    }

    #pragma unroll
    for (int i = 0; i < 2; ++i) {
        #pragma unroll
        for (int r = 0; r < 4; ++r) {
            int row = m0 + wm * 32 + i * 16 + quad * 4 + r;
            #pragma unroll
            for (int j = 0; j < 2; ++j) {
                int col = n0 + wn * 32 + j * 16 + lane15;
                size_t idx = (size_t)row * N + col;
                float v = acc[i][j][r];
                if (resid) v += resid[idx];
                C[idx] = v;
            }
        }
    }
}

// causal depthwise conv + silu: one thread per (b,c); bf16 in/out
__global__ __launch_bounds__(256)
void k_conv(const u16* __restrict__ urb, const float* __restrict__ cw,
            const float* __restrict__ cb, u16* __restrict__ ubf) {
    int idx = blockIdx.x * 256 + threadIdx.x;   // b*DINNER + c
    int c = idx % DINNER;
    int b = idx / DINNER;
    const u16* up = urb + (size_t)(b * SEQ) * NPROJ + c;
    float xv[SEQ];
    #pragma unroll
    for (int v = 0; v < SEQ; ++v) xv[v] = bf2f(up[(size_t)v * NPROJ]);
    float w0 = cw[c * 4 + 0], w1 = cw[c * 4 + 1];
    float w2 = cw[c * 4 + 2], w3 = cw[c * 4 + 3];
    float bias = cb[c];
    u16* op = ubf + (size_t)(b * SEQ) * DINNER + c;
    float x0 = 0.f, x1 = 0.f, x2 = 0.f;
    #pragma unroll
    for (int v = 0; v < SEQ; ++v) {
        float x3 = xv[v];
        float o = bias + w0 * x0 + w1 * x1 + w2 * x2 + w3 * x3;
        op[(size_t)v * DINNER] = f2bf(siluf(o));
        x0 = x1; x1 = x2; x2 = x3;
    }
}

// x_proj: split-K bf16 MFMA. A=ubf [MTOK,DINNER], B=wbx [80,DINNER].
// Grid (KSEGS=8, MTOK/64), 256 thr. Writes fp32 partials dblp[seg][MTOK][80].
__global__ __launch_bounds__(256)
void k_xproj(const u16* __restrict__ ubf, const u16* __restrict__ wbx,
             float* __restrict__ dblp) {
    __shared__ u16 As[64 * 32];
    __shared__ u16 Bs[NDBLP * 32];
    const int t = threadIdx.x;
    const int w = t >> 6, l = t & 63;
    const int lane15 = l & 15, quad = l >> 4;
    const int seg = blockIdx.x;
    const int m0 = blockIdx.y * 64;
    const int kb = seg * KSEG;

    f32x4 acc[5];
    #pragma unroll
    for (int j = 0; j < 5; ++j) acc[j] = (f32x4){0.f, 0.f, 0.f, 0.f};

    for (int k0 = 0; k0 < KSEG; k0 += 32) {
        __syncthreads();
        {
            int c = t;
            const u16* ga = ubf + (size_t)(m0 + (c >> 2)) * DINNER + kb + k0 + (c & 3) * 8;
            __builtin_amdgcn_global_load_lds(
                (const __attribute__((address_space(1))) void*)ga,
                (__attribute__((address_space(3))) void*)&As[c * 8], 16, 0, 0);
            const u16* gb = wbx + (size_t)(c >> 2) * DINNER + kb + k0 + (c & 3) * 8;
            __builtin_amdgcn_global_load_lds(
                (const __attribute__((address_space(1))) void*)gb,
                (__attribute__((address_space(3))) void*)&Bs[c * 8], 16, 0, 0);
        }
        if (t < 64) {
            int c = 256 + t;
            const u16* gb = wbx + (size_t)(c >> 2) * DINNER + kb + k0 + (c & 3) * 8;
            __builtin_amdgcn_global_load_lds(
                (const __attribute__((address_space(1))) void*)gb,
                (__attribute__((address_space(3))) void*)&Bs[c * 8], 16, 0, 0);
        }
        __syncthreads();

        bf16x8 af = *(const bf16x8*)&As[(w * 16 + lane15) * 32 + quad * 8];
        #pragma unroll
        for (int j = 0; j < 5; ++j) {
            bf16x8 bfrag = *(const bf16x8*)&Bs[(j * 16 + lane15) * 32 + quad * 8];
            acc[j] = __builtin_amdgcn_mfma_f32_16x16x32_bf16(af, bfrag, acc[j], 0, 0, 0);
        }
    }

    float* outp = dblp + (size_t)seg * MTOK * NDBLP;
    #pragma unroll
    for (int r = 0; r < 4; ++r) {
        int row = m0 + w * 16 + quad * 4 + r;
        #pragma unroll
        for (int j = 0; j < 5; ++j) {
            int col = j * 16 + lane15;
            outp[(size_t)row * NDBLP + col] = acc[j][r];
        }
    }
}

// Fused dt-GEMM + selective scan, one block per (d-tile of 256, batch).
// Phase A: sum split-K dbl partials for batch b into LDS (dblS [32][80]).
// Phase B: delta = softplus(dbl[:,0:40] . dtw^T + dtb) via MFMA
//          (M=32 pad, N=256, K=64 pad) -> deltaL f32 in LDS.
// Phase C: per-channel scan (one thread per d), delta/B/C from LDS.
__global__ __launch_bounds__(256)
void k_dtscan(const u16* __restrict__ ubf, const u16* __restrict__ urb,
              const float* __restrict__ dblp, const u16* __restrict__ dtwb,
              const float* __restrict__ dtb,
              const float* __restrict__ A_log, const float* __restrict__ Dsk,
              u16* __restrict__ y) {
    __shared__ float dblS[32][NDBLP];      // 10.24 KB (rows 30,31 zero)
    __shared__ u16   As[2 * 32 * 32];      // 4 KB: two 32x32 K-panels
    __shared__ u16   Bs[256 * DTKP];       // 32 KB
    __shared__ float deltaL[32 * 256];     // 32 KB
    const int t = threadIdx.x;
    const int d0 = blockIdx.x * 256;       // channel base
    const int b  = blockIdx.y;
    const int w = t >> 6, l = t & 63;
    const int lane15 = l & 15, quad = l >> 4;

    // ---- Phase A: sum partials
    for (int e = t; e < 32 * NDBLP; e += 256) {
        int v = e / NDBLP, col = e % NDBLP;
        float s = 0.f;
        if (v < SEQ && col < NDBL) {
            #pragma unroll
            for (int sg = 0; sg < KSEGS; ++sg)
                s += dblp[(size_t)sg * MTOK * NDBLP + (size_t)(b * SEQ + v) * NDBLP + col];
        }
        dblS[v][col] = s;
    }
    // stage B tile (dtw bf16 [256 d][64 k]): 256 rows x 8 chunks of 16B = 2048
    #pragma unroll
    for (int it = 0; it < 8; ++it) {
        int c = it * 256 + t;              // 0..2047
        const u16* gb = dtwb + (size_t)(d0 + (c >> 3)) * DTKP + (c & 7) * 8;
        __builtin_amdgcn_global_load_lds(
            (const __attribute__((address_space(1))) void*)gb,
            (__attribute__((address_space(3))) void*)&Bs[c * 8], 16, 0, 0);
    }
    __syncthreads();

    // build A panels (bf16): A[m=v][k=c], zero for c>=40 / v>=30
    for (int e = t; e < 2048; e += 256) {
        int r = e >> 6, c = e & 63;
        float val = (c < DTRANK) ? dblS[r][c] : 0.f;
        As[(c >> 5) * 1024 + r * 32 + (c & 31)] = f2bf(val);
    }
    __syncthreads();

    // ---- Phase B: MFMA delta
    f32x4 acc[2][4];
    #pragma unroll
    for (int i = 0; i < 2; ++i)
        #pragma unroll
        for (int j = 0; j < 4; ++j)
            acc[i][j] = (f32x4){0.f, 0.f, 0.f, 0.f};
    #pragma unroll
    for (int ks = 0; ks < 2; ++ks) {
        bf16x8 af[2];
        #pragma unroll
        for (int mt = 0; mt < 2; ++mt)
            af[mt] = *(const bf16x8*)&As[ks * 1024 + (mt * 16 + lane15) * 32 + quad * 8];
        #pragma unroll
        for (int j = 0; j < 4; ++j) {
            int n = w * 64 + j * 16 + lane15;
            bf16x8 bf = *(const bf16x8*)&Bs[n * DTKP + ks * 32 + quad * 8];
            #pragma unroll
            for (int mt = 0; mt < 2; ++mt)
                acc[mt][j] = __builtin_amdgcn_mfma_f32_16x16x32_bf16(
                    af[mt], bf, acc[mt][j], 0, 0, 0);
        }
    }
    #pragma unroll
    for (int mt = 0; mt < 2; ++mt) {
        #pragma unroll
        for (int j = 0; j < 4; ++j) {
            int col = w * 64 + j * 16 + lane15;
            float bias = dtb[d0 + col];
            #pragma unroll
            for (int r = 0; r < 4; ++r) {
                int row = mt * 16 + quad * 4 + r;
                float vv = acc[mt][j][r] + bias;
                vv = (vv > 20.f) ? vv : log1pf(__expf(vv));
                deltaL[row * 256 + col] = vv;
            }
        }
    }
    __syncthreads();

    // ---- Phase C: scan (one thread per channel)
    const int dch = d0 + t;
    float dl[SEQ], uu[SEQ], rr[SEQ];
    #pragma unroll
    for (int v = 0; v < SEQ; ++v) dl[v] = deltaL[v * 256 + t];
    #pragma unroll
    for (int v = 0; v < SEQ; ++v)
        uu[v] = bf2f(ubf[(size_t)(b * SEQ + v) * DINNER + dch]);
    #pragma unroll
    for (int v = 0; v < SEQ; ++v)
        rr[v] = bf2f(urb[(size_t)(b * SEQ + v) * NPROJ + DINNER + dch]);

    float Ar[DSTATE];
    #pragma unroll
    for (int s = 0; s < DSTATE; ++s)
        Ar[s] = -__expf(A_log[(size_t)dch * DSTATE + s]);
    float dsk = Dsk[dch];
    float st[DSTATE];
    #pragma unroll
    for (int s = 0; s < DSTATE; ++s) st[s] = 0.f;

    u16* yp = y + (size_t)(b * SEQ) * DINNER + dch;

    #pragma unroll
    for (int v = 0; v < SEQ; ++v) {
        float dlt = dl[v];
        float du  = dlt * uu[v];
        float ya0 = 0.f, ya1 = 0.f, ya2 = 0.f, ya3 = 0.f;
        #pragma unroll
        for (int s = 0; s < DSTATE; s += 4) {
            float dA0 = __expf(dlt * Ar[s + 0]);
            float dA1 = __expf(dlt * Ar[s + 1]);
            float dA2 = __expf(dlt * Ar[s + 2]);
            float dA3 = __expf(dlt * Ar[s + 3]);
            st[s + 0] = dA0 * st[s + 0] + du * dblS[v][DTRANK + s + 0];
            st[s + 1] = dA1 * st[s + 1] + du * dblS[v][DTRANK + s + 1];
            st[s + 2] = dA2 * st[s + 2] + du * dblS[v][DTRANK + s + 2];
            st[s + 3] = dA3 * st[s + 3] + du * dblS[v][DTRANK + s + 3];
            ya0 += st[s + 0] * dblS[v][DTRANK + DSTATE + s + 0];
            ya1 += st[s + 1] * dblS[v][DTRANK + DSTATE + s + 1];
            ya2 += st[s + 2] * dblS[v][DTRANK + DSTATE + s + 2];
            ya3 += st[s + 3] * dblS[v][DTRANK + DSTATE + s + 3];
        }
        float ya = (ya0 + ya1) + (ya2 + ya3);
        yp[(size_t)v * DINNER] = f2bf((ya + uu[v] * dsk) * siluf(rr[v]));
    }
}

// final rmsnorm fused with reverse permutation
__global__ __launch_bounds__(64)
void k_final(const float* __restrict__ h, const int* __restrict__ vs,
             const float* __restrict__ w, float* __restrict__ out) {
    int mv = blockIdx.x;
    int v = mv % SEQ, b = mv / SEQ;
    int src = (v + vs[b]) % SEQ;
    const float* row = h + (size_t)(b * SEQ + src) * DMODEL;
    int t = threadIdx.x;
    float ss = 0.f;
    for (int d = t; d < DMODEL; d += 64) { float x = row[d]; ss += x * x; }
    #pragma unroll
    for (int o = 32; o > 0; o >>= 1) ss += __shfl_xor(ss, o, 64);
    float sc = rsqrtf(ss / DMODEL + 1e-5f);
    float* op = out + (size_t)mv * DMODEL;
    for (int d = t; d < DMODEL; d += 64) op[d] = row[d] * sc * w[d];
}

extern "C" void kernel_launch(void* const* d_in, const int* in_sizes, int n_in,
                              void* d_out, int out_size, void* d_ws, size_t ws_size,
                              hipStream_t stream) {
    const float* x      = (const float*)d_in[0];
    const int*   vs     = (const int*)d_in[1];
    const float* norm_w = (const float*)d_in[2];
    const float* in_w   = (const float*)d_in[3];
    const float* conv_w = (const float*)d_in[4];
    const float* conv_b = (const float*)d_in[5];
    const float* xp_w   = (const float*)d_in[6];
    const float* dt_w   = (const float*)d_in[7];
    const float* dt_b   = (const float*)d_in[8];
    const float* A_log  = (const float*)d_in[9];
    const float* Dsk    = (const float*)d_in[10];
    const float* out_w  = (const float*)d_in[11];
    const float* nfw    = (const float*)d_in[12];
    float* out = (float*)d_out;

    char* p = (char*)d_ws;
    float* h      = (float*)p; p += (size_t)MTOK * DMODEL * 4;
    u16*   xn     = (u16*)p;   p += (size_t)MTOK * DMODEL * 2;
    u16*   urb    = (u16*)p;   p += (size_t)MTOK * NPROJ * 2;
    u16*   ubf    = (u16*)p;   p += (size_t)MTOK * DINNER * 2;
    float* dblp   = (float*)p; p += (size_t)KSEGS * MTOK * NDBLP * 4;
    u16*   y      = (u16*)p;   p += (size_t)MTOK * DINNER * 2;
    u16*   wbi4   = (u16*)p;   p += (size_t)NLAYER * NPROJ * DMODEL * 2;
    u16*   wbo4   = (u16*)p;   p += (size_t)NLAYER * DMODEL * DINNER * 2;
    u16*   wbx4   = (u16*)p;   p += (size_t)NLAYER * NDBLP * DINNER * 2;
    u16*   wdt4   = (u16*)p;   p += (size_t)NLAYER * DINNER * DTKP * 2;

    // all weight conversions in one launch
    k_wconv<<<WCTOT / 256, 256, 0, stream>>>(
        in_w, out_w, xp_w, dt_w, wbi4, wbo4, wbx4, wdt4);

    k_permute<<<(MTOK * DMODEL + 255) / 256, 256, 0, stream>>>(x, vs, h);

    for (int l = 0; l < NLAYER; ++l) {
        k_rmsnorm<<<MTOK, 64, 0, stream>>>(h, norm_w + (size_t)l * DMODEL, xn);

        k_mfma512<<<dim3(NPROJ / 128, MTOK / 128), 512, 0, stream>>>(
            xn, DMODEL, wbi4 + (size_t)l * NPROJ * DMODEL, urb, NPROJ, DMODEL);

        k_conv<<<BATCH * DINNER / 256, 256, 0, stream>>>(
            urb, conv_w + (size_t)l * DINNER * DCONV, conv_b + (size_t)l * DINNER, ubf);

        k_xproj<<<dim3(KSEGS, MTOK / 64), 256, 0, stream>>>(
            ubf, wbx4 + (size_t)l * NDBLP * DINNER, dblp);

        k_dtscan<<<dim3(DINNER / 256, BATCH), 256, 0, stream>>>(
            ubf, urb, dblp, wdt4 + (size_t)l * DINNER * DTKP,
            dt_b + (size_t)l * DINNER,
            A_log + (size_t)l * DINNER * DSTATE, Dsk + (size_t)l * DINNER, y);

        k_mfma64<<<dim3(DMODEL / 64, MTOK / 64), 256, 0, stream>>>(
            y, DINNER, wbo4 + (size_t)l * DMODEL * DINNER, h, h, DMODEL, DINNER);
    }

    k_final<<<MTOK, 64, 0, stream>>>(h, vs, nfw, out);
}

// Round 13
// 500.636 us; speedup vs baseline: 1.0198x; 1.0198x over previous
//
#include <hip/hip_runtime.h>
#include <math.h>

#define NLAYER 4
#define DMODEL 640
#define DINNER 1280
#define DSTATE 16
#define DTRANK 40
#define DCONV  4
#define BATCH  64
#define SEQ    30
#define MTOK   (BATCH*SEQ)       // 1920
#define NPROJ  (2*DINNER)        // 2560
#define NDBL   (DTRANK+2*DSTATE) // 72
#define NDBLP  80                // padded N for x_proj MFMA
#define KSEGS  8
#define KSEG   (DINNER/KSEGS)    // 160
#define DTKP   64                // padded K for dt GEMM

// weight-conversion region sizes (in float4 quads)
#define Q1 (NLAYER*NPROJ*DMODEL/4)   // 1,638,400
#define Q2 (NLAYER*DMODEL*DINNER/4)  //   819,200
#define Q3 (NLAYER*NDBLP*DINNER/4)   //   102,400
#define Q4 (NLAYER*DINNER*DTKP/4)    //    81,920
#define WCTOT (Q1+Q2+Q3+Q4)          // 2,641,920 = 256*10320

typedef unsigned short u16;
typedef __bf16 bf16x8 __attribute__((ext_vector_type(8)));
typedef float  f32x4  __attribute__((ext_vector_type(4)));
typedef unsigned short u16x8 __attribute__((ext_vector_type(8)));

__device__ __forceinline__ float siluf(float x) {
    return x / (1.0f + __expf(-x));
}

__device__ __forceinline__ u16 f2bf(float f) {
    unsigned int u = __float_as_uint(f);
    u += 0x7fffu + ((u >> 16) & 1u);
    return (u16)(u >> 16);
}

__device__ __forceinline__ float bf2f(u16 b) {
    return __uint_as_float(((unsigned int)b) << 16);
}

// h[b,v,:] = x[b,(v + SEQ - vs[b]) % SEQ, :]
__global__ void k_permute(const float* __restrict__ x, const int* __restrict__ vs,
                          float* __restrict__ h) {
    int idx = blockIdx.x * blockDim.x + threadIdx.x;
    if (idx >= MTOK * DMODEL) return;
    int d  = idx % DMODEL;
    int mv = idx / DMODEL;
    int v  = mv % SEQ;
    int b  = mv / SEQ;
    int src = (v + SEQ - vs[b]) % SEQ;
    h[idx] = x[(b * SEQ + src) * DMODEL + d];
}

// single weight-conversion kernel: all bf16 weight buffers in one launch.
__global__ __launch_bounds__(256)
void k_wconv(const float* __restrict__ in_w, const float* __restrict__ out_w,
             const float* __restrict__ xp_w, const float* __restrict__ dt_w,
             u16* __restrict__ wbi, u16* __restrict__ wbo,
             u16* __restrict__ wbx, u16* __restrict__ wdt) {
    int i = blockIdx.x * 256 + threadIdx.x;
    if (i < Q1) {
        int j = i * 4;
        float4 v = *(const float4*)(in_w + j);
        ushort4 o;
        o.x = f2bf(v.x); o.y = f2bf(v.y); o.z = f2bf(v.z); o.w = f2bf(v.w);
        *(ushort4*)(wbi + j) = o;
    } else if (i < Q1 + Q2) {
        int j = (i - Q1) * 4;
        float4 v = *(const float4*)(out_w + j);
        ushort4 o;
        o.x = f2bf(v.x); o.y = f2bf(v.y); o.z = f2bf(v.z); o.w = f2bf(v.w);
        *(ushort4*)(wbo + j) = o;
    } else if (i < Q1 + Q2 + Q3) {
        int j = (i - Q1 - Q2) * 4;
        int layer = j / (NDBLP * DINNER);
        int rem   = j % (NDBLP * DINNER);
        int r = rem / DINNER, c = rem % DINNER;
        ushort4 o = make_ushort4(0, 0, 0, 0);
        if (r < NDBL) {
            float4 v = *(const float4*)(xp_w + ((size_t)layer * NDBL + r) * DINNER + c);
            o.x = f2bf(v.x); o.y = f2bf(v.y); o.z = f2bf(v.z); o.w = f2bf(v.w);
        }
        *(ushort4*)(wbx + j) = o;
    } else {
        int j = (i - Q1 - Q2 - Q3) * 4;
        int ld = j / DTKP;      // layer*1280 + d
        int c  = j % DTKP;
        ushort4 o = make_ushort4(0, 0, 0, 0);
        if (c < DTRANK) {
            float4 v = *(const float4*)(dt_w + (size_t)ld * DTRANK + c);
            o.x = f2bf(v.x); o.y = f2bf(v.y); o.z = f2bf(v.z); o.w = f2bf(v.w);
        }
        *(ushort4*)(wdt + j) = o;
    }
}

// one wave per token: xn_bf16 = h * rsqrt(mean(h^2)+eps) * w  (float2 loads)
__global__ __launch_bounds__(64)
void k_rmsnorm(const float* __restrict__ h, const float* __restrict__ w,
               u16* __restrict__ xn) {
    int m = blockIdx.x;
    int t = threadIdx.x;
    const float* row = h + (size_t)m * DMODEL;
    float2 vv[5];
    float ss = 0.f;
    #pragma unroll
    for (int i = 0; i < 5; ++i) {
        vv[i] = *(const float2*)(row + i * 128 + t * 2);
        ss += vv[i].x * vv[i].x + vv[i].y * vv[i].y;
    }
    #pragma unroll
    for (int o = 32; o > 0; o >>= 1) ss += __shfl_xor(ss, o, 64);
    float sc = rsqrtf(ss / DMODEL + 1e-5f);
    u16* outp = xn + (size_t)m * DMODEL;
    #pragma unroll
    for (int i = 0; i < 5; ++i) {
        int d = i * 128 + t * 2;
        float2 wv = *(const float2*)(w + d);
        ushort2 o;
        o.x = f2bf(vv[i].x * sc * wv.x);
        o.y = f2bf(vv[i].y * sc * wv.y);
        *(ushort2*)(outp + d) = o;
    }
}

// 128x128-tile bf16 MFMA GEMM, 512 threads (8 waves, 32x64 per wave).
// bf16 output. Used for in_proj. Grid (N/128, M/128).
__global__ __launch_bounds__(512)
void k_mfma512(const u16* __restrict__ A, int lda,
               const u16* __restrict__ W,
               u16* __restrict__ Cb, int N, int K) {
    __shared__ u16 As[128 * 32];
    __shared__ u16 Bs[128 * 32];
    const int t = threadIdx.x;
    const int w = t >> 6, l = t & 63;
    const int lane15 = l & 15, quad = l >> 4;
    const int wm = w >> 1, wn = w & 1;     // wm 0..3, wn 0..1
    const int m0 = blockIdx.y * 128, n0 = blockIdx.x * 128;

    f32x4 acc[2][4];
    #pragma unroll
    for (int i = 0; i < 2; ++i)
        #pragma unroll
        for (int j = 0; j < 4; ++j)
            acc[i][j] = (f32x4){0.f, 0.f, 0.f, 0.f};

    for (int k0 = 0; k0 < K; k0 += 32) {
        __syncthreads();
        #pragma unroll
        for (int q = 0; q < 2; ++q) {
            int c = q * 512 + t;               // 0..1023
            if (c < 512) {                     // A-tile: 128 rows x 4 chunks
                const u16* ga = A + (size_t)(m0 + (c >> 2)) * lda + k0 + (c & 3) * 8;
                __builtin_amdgcn_global_load_lds(
                    (const __attribute__((address_space(1))) void*)ga,
                    (__attribute__((address_space(3))) void*)&As[c * 8], 16, 0, 0);
            } else {
                int cb = c - 512;
                const u16* gb = W + (size_t)(n0 + (cb >> 2)) * K + k0 + (cb & 3) * 8;
                __builtin_amdgcn_global_load_lds(
                    (const __attribute__((address_space(1))) void*)gb,
                    (__attribute__((address_space(3))) void*)&Bs[cb * 8], 16, 0, 0);
            }
        }
        __syncthreads();

        bf16x8 af[2], bfrag[4];
        #pragma unroll
        for (int i = 0; i < 2; ++i)
            af[i] = *(const bf16x8*)&As[(wm * 32 + i * 16 + lane15) * 32 + quad * 8];
        #pragma unroll
        for (int j = 0; j < 4; ++j)
            bfrag[j] = *(const bf16x8*)&Bs[(wn * 64 + j * 16 + lane15) * 32 + quad * 8];
        #pragma unroll
        for (int i = 0; i < 2; ++i)
            #pragma unroll
            for (int j = 0; j < 4; ++j)
                acc[i][j] = __builtin_amdgcn_mfma_f32_16x16x32_bf16(
                    af[i], bfrag[j], acc[i][j], 0, 0, 0);
    }

    #pragma unroll
    for (int i = 0; i < 2; ++i) {
        #pragma unroll
        for (int r = 0; r < 4; ++r) {
            int row = m0 + wm * 32 + i * 16 + quad * 4 + r;
            #pragma unroll
            for (int j = 0; j < 4; ++j) {
                int col = n0 + wn * 64 + j * 16 + lane15;
                Cb[(size_t)row * N + col] = f2bf(acc[i][j][r]);
            }
        }
    }
}

// 64x64-tile bf16 MFMA GEMM, f32 out + resid (out_proj)
__global__ __launch_bounds__(256)
void k_mfma64(const u16* __restrict__ A, int lda,
              const u16* __restrict__ W,
              const float* __restrict__ resid,
              float* __restrict__ C, int N, int K) {
    __shared__ u16 As[64 * 32];
    __shared__ u16 Bs[64 * 32];
    const int t = threadIdx.x;
    const int w = t >> 6, l = t & 63;
    const int lane15 = l & 15, quad = l >> 4;
    const int wm = w >> 1, wn = w & 1;
    const int m0 = blockIdx.y * 64, n0 = blockIdx.x * 64;

    f32x4 acc[2][2];
    #pragma unroll
    for (int i = 0; i < 2; ++i)
        #pragma unroll
        for (int j = 0; j < 2; ++j)
            acc[i][j] = (f32x4){0.f, 0.f, 0.f, 0.f};

    for (int k0 = 0; k0 < K; k0 += 32) {
        __syncthreads();
        {
            int c = t;
            const u16* ga = A + (size_t)(m0 + (c >> 2)) * lda + k0 + (c & 3) * 8;
            __builtin_amdgcn_global_load_lds(
                (const __attribute__((address_space(1))) void*)ga,
                (__attribute__((address_space(3))) void*)&As[c * 8], 16, 0, 0);
            const u16* gb = W + (size_t)(n0 + (c >> 2)) * K + k0 + (c & 3) * 8;
            __builtin_amdgcn_global_load_lds(
                (const __attribute__((address_space(1))) void*)gb,
                (__attribute__((address_space(3))) void*)&Bs[c * 8], 16, 0, 0);
        }
        __syncthreads();

        bf16x8 af[2], bfrag[2];
        #pragma unroll
        for (int i = 0; i < 2; ++i)
            af[i] = *(const bf16x8*)&As[(wm * 32 + i * 16 + lane15) * 32 + quad * 8];
        #pragma unroll
        for (int j = 0; j < 2; ++j)
            bfrag[j] = *(const bf16x8*)&Bs[(wn * 32 + j * 16 + lane15) * 32 + quad * 8];
        #pragma unroll
        for (int i = 0; i < 2; ++i)
            #pragma unroll
            for (int j = 0; j < 2; ++j)
                acc[i][j] = __builtin_amdgcn_mfma_f32_16x16x32_bf16(
                    af[i], bfrag[j], acc[i][j], 0, 0, 0);
    }

    #pragma unroll
    for (int i = 0; i < 2; ++i) {
        #pragma unroll
        for (int r = 0; r < 4; ++r) {
            int row = m0 + wm * 32 + i * 16 + quad * 4 + r;
            #pragma unroll
            for (int j = 0; j < 2; ++j) {
                int col = n0 + wn * 32 + j * 16 + lane15;
                size_t idx = (size_t)row * N + col;
                float v = acc[i][j][r];
                if (resid) v += resid[idx];
                C[idx] = v;
            }
        }
    }
}

// causal depthwise conv + silu: one thread per (b,c); bf16 in/out
__global__ __launch_bounds__(256)
void k_conv(const u16* __restrict__ urb, const float* __restrict__ cw,
            const float* __restrict__ cb, u16* __restrict__ ubf) {
    int idx = blockIdx.x * 256 + threadIdx.x;   // b*DINNER + c
    int c = idx % DINNER;
    int b = idx / DINNER;
    const u16* up = urb + (size_t)(b * SEQ) * NPROJ + c;
    float xv[SEQ];
    #pragma unroll
    for (int v = 0; v < SEQ; ++v) xv[v] = bf2f(up[(size_t)v * NPROJ]);
    float w0 = cw[c * 4 + 0], w1 = cw[c * 4 + 1];
    float w2 = cw[c * 4 + 2], w3 = cw[c * 4 + 3];
    float bias = cb[c];
    u16* op = ubf + (size_t)(b * SEQ) * DINNER + c;
    float x0 = 0.f, x1 = 0.f, x2 = 0.f;
    #pragma unroll
    for (int v = 0; v < SEQ; ++v) {
        float x3 = xv[v];
        float o = bias + w0 * x0 + w1 * x1 + w2 * x2 + w3 * x3;
        op[(size_t)v * DINNER] = f2bf(siluf(o));
        x0 = x1; x1 = x2; x2 = x3;
    }
}

// x_proj: split-K bf16 MFMA. A=ubf [MTOK,DINNER], B=wbx [80,DINNER].
// Grid (KSEGS=8, MTOK/64), 256 thr. Writes fp32 partials dblp[seg][MTOK][80].
__global__ __launch_bounds__(256)
void k_xproj(const u16* __restrict__ ubf, const u16* __restrict__ wbx,
             float* __restrict__ dblp) {
    __shared__ u16 As[64 * 32];
    __shared__ u16 Bs[NDBLP * 32];
    const int t = threadIdx.x;
    const int w = t >> 6, l = t & 63;
    const int lane15 = l & 15, quad = l >> 4;
    const int seg = blockIdx.x;
    const int m0 = blockIdx.y * 64;
    const int kb = seg * KSEG;

    f32x4 acc[5];
    #pragma unroll
    for (int j = 0; j < 5; ++j) acc[j] = (f32x4){0.f, 0.f, 0.f, 0.f};

    for (int k0 = 0; k0 < KSEG; k0 += 32) {
        __syncthreads();
        {
            int c = t;
            const u16* ga = ubf + (size_t)(m0 + (c >> 2)) * DINNER + kb + k0 + (c & 3) * 8;
            __builtin_amdgcn_global_load_lds(
                (const __attribute__((address_space(1))) void*)ga,
                (__attribute__((address_space(3))) void*)&As[c * 8], 16, 0, 0);
            const u16* gb = wbx + (size_t)(c >> 2) * DINNER + kb + k0 + (c & 3) * 8;
            __builtin_amdgcn_global_load_lds(
                (const __attribute__((address_space(1))) void*)gb,
                (__attribute__((address_space(3))) void*)&Bs[c * 8], 16, 0, 0);
        }
        if (t < 64) {
            int c = 256 + t;
            const u16* gb = wbx + (size_t)(c >> 2) * DINNER + kb + k0 + (c & 3) * 8;
            __builtin_amdgcn_global_load_lds(
                (const __attribute__((address_space(1))) void*)gb,
                (__attribute__((address_space(3))) void*)&Bs[c * 8], 16, 0, 0);
        }
        __syncthreads();

        bf16x8 af = *(const bf16x8*)&As[(w * 16 + lane15) * 32 + quad * 8];
        #pragma unroll
        for (int j = 0; j < 5; ++j) {
            bf16x8 bfrag = *(const bf16x8*)&Bs[(j * 16 + lane15) * 32 + quad * 8];
            acc[j] = __builtin_amdgcn_mfma_f32_16x16x32_bf16(af, bfrag, acc[j], 0, 0, 0);
        }
    }

    float* outp = dblp + (size_t)seg * MTOK * NDBLP;
    #pragma unroll
    for (int r = 0; r < 4; ++r) {
        int row = m0 + w * 16 + quad * 4 + r;
        #pragma unroll
        for (int j = 0; j < 5; ++j) {
            int col = j * 16 + lane15;
            outp[(size_t)row * NDBLP + col] = acc[j][r];
        }
    }
}

// dt GEMM with inline split-K prep: A[m][k] = sum_seg dblp (bf16), K=64 (pad).
// delta_bf16[m,d] = softplus(A·dtwb[d] + dtb[d]). Grid (20,30), 256 thr.
__global__ __launch_bounds__(256)
void k_dtgemm(const float* __restrict__ dblp, const u16* __restrict__ dtwb,
              const float* __restrict__ dtb, u16* __restrict__ delta) {
    __shared__ u16 As[64 * 32];
    __shared__ u16 Bs[64 * 32];
    const int t = threadIdx.x;
    const int w = t >> 6, l = t & 63;
    const int lane15 = l & 15, quad = l >> 4;
    const int wm = w >> 1, wn = w & 1;
    const int m0 = blockIdx.y * 64, n0 = blockIdx.x * 64;
    const int row = t >> 2, koff = (t & 3) * 8;
    const int m = m0 + row;

    f32x4 acc[2][2];
    #pragma unroll
    for (int i = 0; i < 2; ++i)
        #pragma unroll
        for (int j = 0; j < 2; ++j)
            acc[i][j] = (f32x4){0.f, 0.f, 0.f, 0.f};

    #pragma unroll
    for (int k0 = 0; k0 < DTKP; k0 += 32) {
        float sums[8] = {0.f, 0.f, 0.f, 0.f, 0.f, 0.f, 0.f, 0.f};
        #pragma unroll
        for (int q = 0; q < 2; ++q) {
            int col = k0 + koff + q * 4;
            if (col < DTRANK) {
                #pragma unroll
                for (int sg = 0; sg < KSEGS; ++sg) {
                    float4 p = *(const float4*)&dblp[(size_t)sg * MTOK * NDBLP
                                                     + (size_t)m * NDBLP + col];
                    sums[q * 4 + 0] += p.x; sums[q * 4 + 1] += p.y;
                    sums[q * 4 + 2] += p.z; sums[q * 4 + 3] += p.w;
                }
            }
        }
        u16x8 av;
        #pragma unroll
        for (int e = 0; e < 8; ++e) av[e] = f2bf(sums[e]);
        __syncthreads();
        *(u16x8*)&As[row * 32 + koff] = av;
        {
            int c = t;
            const u16* gb = dtwb + (size_t)(n0 + (c >> 2)) * DTKP + k0 + (c & 3) * 8;
            __builtin_amdgcn_global_load_lds(
                (const __attribute__((address_space(1))) void*)gb,
                (__attribute__((address_space(3))) void*)&Bs[c * 8], 16, 0, 0);
        }
        __syncthreads();

        bf16x8 af[2], bfrag[2];
        #pragma unroll
        for (int i = 0; i < 2; ++i)
            af[i] = *(const bf16x8*)&As[(wm * 32 + i * 16 + lane15) * 32 + quad * 8];
        #pragma unroll
        for (int j = 0; j < 2; ++j)
            bfrag[j] = *(const bf16x8*)&Bs[(wn * 32 + j * 16 + lane15) * 32 + quad * 8];
        #pragma unroll
        for (int i = 0; i < 2; ++i)
            #pragma unroll
            for (int j = 0; j < 2; ++j)
                acc[i][j] = __builtin_amdgcn_mfma_f32_16x16x32_bf16(
                    af[i], bfrag[j], acc[i][j], 0, 0, 0);
    }

    #pragma unroll
    for (int i = 0; i < 2; ++i) {
        #pragma unroll
        for (int r = 0; r < 4; ++r) {
            int orow = m0 + wm * 32 + i * 16 + quad * 4 + r;
            #pragma unroll
            for (int j = 0; j < 2; ++j) {
                int col = n0 + wn * 32 + j * 16 + lane15;
                float vv = acc[i][j][r] + dtb[col];
                vv = (vv > 20.f) ? vv : log1pf(__expf(vv));
                delta[(size_t)orow * DINNER + col] = f2bf(vv);
            }
        }
    }
}

// selective scan, one thread per (b,d); delta bf16; inputs prefetched.
__global__ __launch_bounds__(256)
void k_scan(const u16* __restrict__ ubf, const u16* __restrict__ urb,
            const float* __restrict__ dblp, const u16* __restrict__ delta,
            const float* __restrict__ A_log, const float* __restrict__ Dsk,
            u16* __restrict__ y) {
    __shared__ float BC[SEQ][2 * DSTATE];
    const int b  = blockIdx.x / (DINNER / 256);
    const int dc = blockIdx.x % (DINNER / 256);
    const int d  = dc * 256 + threadIdx.x;

    for (int t = threadIdx.x; t < SEQ * 2 * DSTATE; t += 256) {
        int v = t >> 5, s = t & 31;
        float acc = 0.f;
        #pragma unroll
        for (int sg = 0; sg < KSEGS; ++sg)
            acc += dblp[(size_t)sg * MTOK * NDBLP + (size_t)(b * SEQ + v) * NDBLP + DTRANK + s];
        BC[v][s] = acc;
    }
    __syncthreads();

    float dl[SEQ], uu[SEQ], rr[SEQ];
    #pragma unroll
    for (int v = 0; v < SEQ; ++v)
        dl[v] = bf2f(delta[(size_t)(b * SEQ + v) * DINNER + d]);
    #pragma unroll
    for (int v = 0; v < SEQ; ++v)
        uu[v] = bf2f(ubf[(size_t)(b * SEQ + v) * DINNER + d]);
    #pragma unroll
    for (int v = 0; v < SEQ; ++v)
        rr[v] = bf2f(urb[(size_t)(b * SEQ + v) * NPROJ + DINNER + d]);

    float Ar[DSTATE];
    #pragma unroll
    for (int s = 0; s < DSTATE; ++s) Ar[s] = -__expf(A_log[(size_t)d * DSTATE + s]);
    float dsk = Dsk[d];
    float st[DSTATE];
    #pragma unroll
    for (int s = 0; s < DSTATE; ++s) st[s] = 0.f;

    u16* yp = y + (size_t)(b * SEQ) * DINNER + d;

    #pragma unroll
    for (int v = 0; v < SEQ; ++v) {
        float dlt = dl[v];
        float du  = dlt * uu[v];
        float ya0 = 0.f, ya1 = 0.f, ya2 = 0.f, ya3 = 0.f;
        #pragma unroll
        for (int s = 0; s < DSTATE; s += 4) {
            float dA0 = __expf(dlt * Ar[s + 0]);
            float dA1 = __expf(dlt * Ar[s + 1]);
            float dA2 = __expf(dlt * Ar[s + 2]);
            float dA3 = __expf(dlt * Ar[s + 3]);
            st[s + 0] = dA0 * st[s + 0] + du * BC[v][s + 0];
            st[s + 1] = dA1 * st[s + 1] + du * BC[v][s + 1];
            st[s + 2] = dA2 * st[s + 2] + du * BC[v][s + 2];
            st[s + 3] = dA3 * st[s + 3] + du * BC[v][s + 3];
            ya0 += st[s + 0] * BC[v][DSTATE + s + 0];
            ya1 += st[s + 1] * BC[v][DSTATE + s + 1];
            ya2 += st[s + 2] * BC[v][DSTATE + s + 2];
            ya3 += st[s + 3] * BC[v][DSTATE + s + 3];
        }
        float ya = (ya0 + ya1) + (ya2 + ya3);
        yp[(size_t)v * DINNER] = f2bf((ya + uu[v] * dsk) * siluf(rr[v]));
    }
}

// final rmsnorm fused with reverse permutation
__global__ __launch_bounds__(64)
void k_final(const float* __restrict__ h, const int* __restrict__ vs,
             const float* __restrict__ w, float* __restrict__ out) {
    int mv = blockIdx.x;
    int v = mv % SEQ, b = mv / SEQ;
    int src = (v + vs[b]) % SEQ;
    const float* row = h + (size_t)(b * SEQ + src) * DMODEL;
    int t = threadIdx.x;
    float ss = 0.f;
    for (int d = t; d < DMODEL; d += 64) { float x = row[d]; ss += x * x; }
    #pragma unroll
    for (int o = 32; o > 0; o >>= 1) ss += __shfl_xor(ss, o, 64);
    float sc = rsqrtf(ss / DMODEL + 1e-5f);
    float* op = out + (size_t)mv * DMODEL;
    for (int d = t; d < DMODEL; d += 64) op[d] = row[d] * sc * w[d];
}

extern "C" void kernel_launch(void* const* d_in, const int* in_sizes, int n_in,
                              void* d_out, int out_size, void* d_ws, size_t ws_size,
                              hipStream_t stream) {
    const float* x      = (const float*)d_in[0];
    const int*   vs     = (const int*)d_in[1];
    const float* norm_w = (const float*)d_in[2];
    const float* in_w   = (const float*)d_in[3];
    const float* conv_w = (const float*)d_in[4];
    const float* conv_b = (const float*)d_in[5];
    const float* xp_w   = (const float*)d_in[6];
    const float* dt_w   = (const float*)d_in[7];
    const float* dt_b   = (const float*)d_in[8];
    const float* A_log  = (const float*)d_in[9];
    const float* Dsk    = (const float*)d_in[10];
    const float* out_w  = (const float*)d_in[11];
    const float* nfw    = (const float*)d_in[12];
    float* out = (float*)d_out;

    char* p = (char*)d_ws;
    float* h      = (float*)p; p += (size_t)MTOK * DMODEL * 4;
    u16*   xn     = (u16*)p;   p += (size_t)MTOK * DMODEL * 2;
    u16*   urb    = (u16*)p;   p += (size_t)MTOK * NPROJ * 2;
    u16*   ubf    = (u16*)p;   p += (size_t)MTOK * DINNER * 2;
    float* dblp   = (float*)p; p += (size_t)KSEGS * MTOK * NDBLP * 4;
    u16*   deltab = (u16*)p;   p += (size_t)MTOK * DINNER * 2;
    u16*   y      = (u16*)p;   p += (size_t)MTOK * DINNER * 2;
    u16*   wbi4   = (u16*)p;   p += (size_t)NLAYER * NPROJ * DMODEL * 2;
    u16*   wbo4   = (u16*)p;   p += (size_t)NLAYER * DMODEL * DINNER * 2;
    u16*   wbx4   = (u16*)p;   p += (size_t)NLAYER * NDBLP * DINNER * 2;
    u16*   wdt4   = (u16*)p;   p += (size_t)NLAYER * DINNER * DTKP * 2;

    // all weight conversions in one launch
    k_wconv<<<WCTOT / 256, 256, 0, stream>>>(
        in_w, out_w, xp_w, dt_w, wbi4, wbo4, wbx4, wdt4);

    k_permute<<<(MTOK * DMODEL + 255) / 256, 256, 0, stream>>>(x, vs, h);

    for (int l = 0; l < NLAYER; ++l) {
        k_rmsnorm<<<MTOK, 64, 0, stream>>>(h, norm_w + (size_t)l * DMODEL, xn);

        k_mfma512<<<dim3(NPROJ / 128, MTOK / 128), 512, 0, stream>>>(
            xn, DMODEL, wbi4 + (size_t)l * NPROJ * DMODEL, urb, NPROJ, DMODEL);

        k_conv<<<BATCH * DINNER / 256, 256, 0, stream>>>(
            urb, conv_w + (size_t)l * DINNER * DCONV, conv_b + (size_t)l * DINNER, ubf);

        k_xproj<<<dim3(KSEGS, MTOK / 64), 256, 0, stream>>>(
            ubf, wbx4 + (size_t)l * NDBLP * DINNER, dblp);

        k_dtgemm<<<dim3(DINNER / 64, MTOK / 64), 256, 0, stream>>>(
            dblp, wdt4 + (size_t)l * DINNER * DTKP,
            dt_b + (size_t)l * DINNER, deltab);

        k_scan<<<BATCH * (DINNER / 256), 256, 0, stream>>>(
            ubf, urb, dblp, deltab,
            A_log + (size_t)l * DINNER * DSTATE, Dsk + (size_t)l * DINNER, y);

        k_mfma64<<<dim3(DMODEL / 64, MTOK / 64), 256, 0, stream>>>(
            y, DINNER, wbo4 + (size_t)l * DMODEL * DINNER, h, h, DMODEL, DINNER);
    }

    k_final<<<MTOK, 64, 0, stream>>>(h, vs, nfw, out);
}